// Round 6
// baseline (288.174 us; speedup 1.0000x reference)
//
#include <hip/hip_runtime.h>

// Problem constants: B=1, T=2048, D=2048, H=16, HD=128
#define TT 2048
#define DD 2048
#define NH 16
#define HDIM 128

typedef _Float16 half8 __attribute__((ext_vector_type(8)));
typedef _Float16 half4 __attribute__((ext_vector_type(4)));
typedef float floatx4 __attribute__((ext_vector_type(4)));

// ---------------------------------------------------------------------------
// Fused prep: z=0 -> straight fp32->f16 convert of x tile;
// z=1..4 -> W[K][N] fp32 -> f16 Wt[N][K] transpose+convert (32x32 LDS tile).
// ---------------------------------------------------------------------------
__global__ __launch_bounds__(256) void prep_kernel(const float* __restrict__ x,
                                                   const float* __restrict__ W1,
                                                   const float* __restrict__ W2,
                                                   const float* __restrict__ W3,
                                                   const float* __restrict__ W4,
                                                   _Float16* __restrict__ xh,
                                                   _Float16* __restrict__ O1,
                                                   _Float16* __restrict__ O2,
                                                   _Float16* __restrict__ O3,
                                                   _Float16* __restrict__ O4) {
    const int tx = threadIdx.x & 7;    // *4 cols
    const int ty = threadIdx.x >> 3;   // 0..31
    const int k0 = blockIdx.y * 32;
    const int n0 = blockIdx.x * 32;
    const int z = blockIdx.z;

    if (z == 0) {  // straight convert
        const float4 v = *(const float4*)(x + (size_t)(k0 + ty) * DD + n0 + tx * 4);
        half4 o;
        o[0] = (_Float16)v.x; o[1] = (_Float16)v.y;
        o[2] = (_Float16)v.z; o[3] = (_Float16)v.w;
        *(half4*)(xh + (size_t)(k0 + ty) * DD + n0 + tx * 4) = o;
        return;
    }
    const float* W = z == 1 ? W1 : (z == 2 ? W2 : (z == 3 ? W3 : W4));
    _Float16* O = z == 1 ? O1 : (z == 2 ? O2 : (z == 3 ? O3 : O4));
    __shared__ float T[32][33];
    const float4 v = *(const float4*)(W + (size_t)(k0 + ty) * DD + n0 + tx * 4);
    T[ty][tx * 4 + 0] = v.x;
    T[ty][tx * 4 + 1] = v.y;
    T[ty][tx * 4 + 2] = v.z;
    T[ty][tx * 4 + 3] = v.w;
    __syncthreads();
    half4 o;
    o[0] = (_Float16)T[tx * 4 + 0][ty];
    o[1] = (_Float16)T[tx * 4 + 1][ty];
    o[2] = (_Float16)T[tx * 4 + 2][ty];
    o[3] = (_Float16)T[tx * 4 + 3][ty];
    *(half4*)(O + (size_t)(n0 + ty) * DD + k0 + tx * 4) = o;
}

// ---------------------------------------------------------------------------
// MFMA f16 GEMM body. Wave->column remap: colmap(j) = (w&1)*32 + (j&1)*16 +
// (j>>1)*64, so RoPE pairs (c, c+64) are acc[i][j] / acc[i][j+2] in the SAME
// lane (in-register rope, no LDS exchange). MODE: 0 = fp32 C[row][col],
// 2 = f16 transposed C[col][row], 3 = f16 C[row][col] with fused RoPE.
// ---------------------------------------------------------------------------
template <int MODE>
__device__ __forceinline__ void hgemm_body(const _Float16* __restrict__ A,
                                           const _Float16* __restrict__ Bt,
                                           float* __restrict__ Cf,
                                           _Float16* __restrict__ Ch,
                                           const float* __restrict__ sn,
                                           const float* __restrict__ cs,
                                           const int row0, const int col0) {
    __shared__ __align__(16) _Float16 Al[128 * 32];
    __shared__ __align__(16) _Float16 Bl[128 * 32];

    const int tid = threadIdx.x;
    const int lane = tid & 63;
    const int w = tid >> 6;
    const int quad = lane >> 4;
    const int lr = lane & 15;
    const int wr = (w >> 1) * 64;
    const int wcb = (w & 1) * 32;   // column base for the remapped layout

    floatx4 acc[4][4];
#pragma unroll
    for (int i = 0; i < 4; ++i)
#pragma unroll
        for (int j = 0; j < 4; ++j)
            acc[i][j] = (floatx4){0.f, 0.f, 0.f, 0.f};

    const int subrow = lane >> 2;
    const int lblk = lane & 3;

    for (int k0 = 0; k0 < DD; k0 += 32) {
#pragma unroll
        for (int i = 0; i < 2; ++i) {
            const int ch = w * 2 + i;
            const int r = ch * 16 + subrow;
            const int gb = (lblk + (r >> 1)) & 3;
            const _Float16* ga = A + (size_t)(row0 + r) * DD + k0 + gb * 8;
            __builtin_amdgcn_global_load_lds(
                (const __attribute__((address_space(1))) void*)ga,
                (__attribute__((address_space(3))) void*)(Al + ch * 512), 16, 0, 0);
            const _Float16* gbp = Bt + (size_t)(col0 + r) * DD + k0 + gb * 8;
            __builtin_amdgcn_global_load_lds(
                (const __attribute__((address_space(1))) void*)gbp,
                (__attribute__((address_space(3))) void*)(Bl + ch * 512), 16, 0, 0);
        }
        __syncthreads();

        half8 af[4], bf[4];
#pragma unroll
        for (int i = 0; i < 4; ++i) {
            const int r = wr + i * 16 + lr;
            const int lb = (quad - (r >> 1)) & 3;
            af[i] = *(const half8*)&Al[r * 32 + lb * 8];
        }
#pragma unroll
        for (int j = 0; j < 4; ++j) {
            const int r = wcb + (j & 1) * 16 + (j >> 1) * 64 + lr;  // colmap(j)+lr
            const int lb = (quad - (r >> 1)) & 3;
            bf[j] = *(const half8*)&Bl[r * 32 + lb * 8];
        }
#pragma unroll
        for (int i = 0; i < 4; ++i)
#pragma unroll
            for (int j = 0; j < 4; ++j)
                acc[i][j] = __builtin_amdgcn_mfma_f32_16x16x32_f16(af[i], bf[j], acc[i][j], 0, 0, 0);
        __syncthreads();
    }

    // epilogue: C/D layout col = colmap(j) + (lane&15), row = quad*4 + reg
    if constexpr (MODE == 3) {
        // fused RoPE: lower half cl = wcb + j*16 + lr (j<2), upper = cl + 64
#pragma unroll
        for (int i = 0; i < 4; ++i)
#pragma unroll
            for (int r = 0; r < 4; ++r) {
                const int t = row0 + wr + i * 16 + quad * 4 + r;  // token index
#pragma unroll
                for (int j = 0; j < 2; ++j) {
                    const int cl = wcb + j * 16 + lr;             // head-local, < 64
                    const float lo = acc[i][j][r];
                    const float hi = acc[i][j + 2][r];
                    const float s1 = sn[t * HDIM + cl];
                    const float c1 = cs[t * HDIM + cl];
                    const float s2 = sn[t * HDIM + cl + 64];
                    const float c2 = cs[t * HDIM + cl + 64];
                    Ch[(size_t)t * DD + col0 + cl]      = (_Float16)(lo * c1 - hi * s1);
                    Ch[(size_t)t * DD + col0 + cl + 64] = (_Float16)(hi * c2 + lo * s2);
                }
            }
    } else {
#pragma unroll
        for (int i = 0; i < 4; ++i)
#pragma unroll
            for (int j = 0; j < 4; ++j) {
                const int col = col0 + wcb + (j & 1) * 16 + (j >> 1) * 64 + lr;
#pragma unroll
                for (int r = 0; r < 4; ++r) {
                    const int row = row0 + wr + i * 16 + quad * 4 + r;
                    if (MODE == 0) Cf[(size_t)row * DD + col] = acc[i][j][r];
                    if (MODE == 2) Ch[(size_t)col * DD + row] = (_Float16)acc[i][j][r];
                }
            }
    }
}

// QKV fused: z=0 -> Qh (f16 + rope), z=1 -> Kh (f16 + rope), z=2 -> Vt (f16^T)
__global__ __launch_bounds__(256) void qkv_gemm_kernel(const _Float16* __restrict__ xh,
                                                       const _Float16* __restrict__ Wqt,
                                                       const _Float16* __restrict__ Wkt,
                                                       const _Float16* __restrict__ Wvt,
                                                       const float* __restrict__ sn,
                                                       const float* __restrict__ cs,
                                                       _Float16* __restrict__ Qh,
                                                       _Float16* __restrict__ Kh,
                                                       _Float16* __restrict__ Vt) {
    const int row0 = blockIdx.y * 128, col0 = blockIdx.x * 128;
    if (blockIdx.z == 0)      hgemm_body<3>(xh, Wqt, nullptr, Qh, sn, cs, row0, col0);
    else if (blockIdx.z == 1) hgemm_body<3>(xh, Wkt, nullptr, Kh, sn, cs, row0, col0);
    else                      hgemm_body<2>(xh, Wvt, nullptr, Vt, nullptr, nullptr, row0, col0);
}

__global__ __launch_bounds__(256) void ogemm_kernel(const _Float16* __restrict__ Ah,
                                                    const _Float16* __restrict__ Wot,
                                                    float* __restrict__ C) {
    hgemm_body<0>(Ah, Wot, C, nullptr, nullptr, nullptr, blockIdx.y * 128, blockIdx.x * 128);
}

// ---------------------------------------------------------------------------
// MFMA flash attention (verified R5, unchanged). Block = 4 waves, BQ=64,
// BS=32. Q frags in registers; K chunk-swizzled via global_load_lds; V from
// pre-transposed Vt[d][t]. P round-trips per-wave LDS. Doc mask via -1e30
// annihilation.
// ---------------------------------------------------------------------------
__global__ __launch_bounds__(256) void attn_kernel(const _Float16* __restrict__ Qh,
                                                   const _Float16* __restrict__ Kh,
                                                   const _Float16* __restrict__ Vt,
                                                   const int* __restrict__ doc_ids,
                                                   _Float16* __restrict__ Aout) {
    __shared__ __align__(16) _Float16 KV[32 * 128 + 128 * 32];  // Kl | Vl (16KB)
    __shared__ __align__(16) _Float16 Ps[4][16 * 40];           // per-wave P
    __shared__ int sdoc[32];
    _Float16* Kl = KV;
    _Float16* Vl = KV + 32 * 128;

    const int tid = threadIdx.x;
    const int lane = tid & 63;
    const int w = tid >> 6;
    const int quad = lane >> 4;
    const int lr = lane & 15;
    const int h = blockIdx.y;
    const int q0 = blockIdx.x * 64;

    // Q fragments (A-layout): row = q0 + w*16 + lr, k = c*32 + quad*8 + j
    const int qrow = q0 + w * 16 + lr;
    half8 qf[4];
#pragma unroll
    for (int c = 0; c < 4; ++c)
        qf[c] = *(const half8*)(Qh + (size_t)qrow * DD + h * HDIM + c * 32 + quad * 8);

    // docs of this lane's C-layout rows (quad*4 + r)
    int qd[4];
#pragma unroll
    for (int r = 0; r < 4; ++r)
        qd[r] = doc_ids[q0 + w * 16 + quad * 4 + r];

    float m_r[4], l_r[4];
    floatx4 Oacc[8];
#pragma unroll
    for (int r = 0; r < 4; ++r) { m_r[r] = -1e30f; l_r[r] = 0.f; }
#pragma unroll
    for (int n = 0; n < 8; ++n) Oacc[n] = (floatx4){0.f, 0.f, 0.f, 0.f};

    // binary search: first index with doc == doc_ids[q0]
    const int d0 = doc_ids[q0];
    int lo = 0, hi = q0;
    while (lo < hi) {
        const int mid = (lo + hi) >> 1;
        if (doc_ids[mid] < d0) lo = mid + 1; else hi = mid;
    }
    const int s_begin = lo & ~31;

    for (int s0 = s_begin; s0 < q0 + 64; s0 += 32) {
        // ---- stage K (chunk-swizzled) + Vt ----
#pragma unroll
        for (int i = 0; i < 2; ++i) {
            const int ch = w * 2 + i;
            {   // K: 4 rows x 256B per instr; LDS[r][p] holds global chunk (p - r)&15
                const int r = ch * 4 + (lane >> 4);
                const int g = ((lane & 15) - r) & 15;
                const _Float16* src = Kh + (size_t)(s0 + r) * DD + h * HDIM + g * 8;
                __builtin_amdgcn_global_load_lds(
                    (const __attribute__((address_space(1))) void*)src,
                    (__attribute__((address_space(3))) void*)(Kl + ch * 512), 16, 0, 0);
            }
            {   // Vt: 16 rows x 64B per instr, natural [d][s] layout
                const int dl = ch * 16 + (lane >> 2);
                const _Float16* src = Vt + (size_t)(h * HDIM + dl) * TT + s0 + (lane & 3) * 8;
                __builtin_amdgcn_global_load_lds(
                    (const __attribute__((address_space(1))) void*)src,
                    (__attribute__((address_space(3))) void*)(Vl + ch * 512), 16, 0, 0);
            }
        }
        if (tid < 32) sdoc[tid] = doc_ids[s0 + tid];
        __syncthreads();

        // ---- S = Q K^T : two 16x16 col-blocks ----
        floatx4 S0 = (floatx4){0.f, 0.f, 0.f, 0.f};
        floatx4 S1 = (floatx4){0.f, 0.f, 0.f, 0.f};
#pragma unroll
        for (int c = 0; c < 4; ++c) {
            const int p = (c * 4 + quad + lr) & 15;
            half8 b0 = *(const half8*)&Kl[(lr) * 128 + p * 8];
            half8 b1 = *(const half8*)&Kl[(16 + lr) * 128 + p * 8];
            S0 = __builtin_amdgcn_mfma_f32_16x16x32_f16(qf[c], b0, S0, 0, 0, 0);
            S1 = __builtin_amdgcn_mfma_f32_16x16x32_f16(qf[c], b1, S1, 0, 0, 0);
        }

        // ---- mask + online softmax (C layout: col=lr, row=quad*4+r) ----
        const float scale = 0.08838834764831845f;
        float alpha[4];
#pragma unroll
        for (int r = 0; r < 4; ++r) {
            const int qg = q0 + w * 16 + quad * 4 + r;
            const bool v0 = (s0 + lr <= qg) && (sdoc[lr] == qd[r]);
            const bool v1 = (s0 + 16 + lr <= qg) && (sdoc[16 + lr] == qd[r]);
            const float x0 = v0 ? S0[r] * scale : -1e30f;
            const float x1 = v1 ? S1[r] * scale : -1e30f;
            float m = fmaxf(x0, x1);
            m = fmaxf(m, __shfl_xor(m, 1));
            m = fmaxf(m, __shfl_xor(m, 2));
            m = fmaxf(m, __shfl_xor(m, 4));
            m = fmaxf(m, __shfl_xor(m, 8));
            const float mn = fmaxf(m_r[r], m);
            const float e0 = __expf(x0 - mn);
            const float e1 = __expf(x1 - mn);
            float ts = e0 + e1;
            ts += __shfl_xor(ts, 1);
            ts += __shfl_xor(ts, 2);
            ts += __shfl_xor(ts, 4);
            ts += __shfl_xor(ts, 8);
            alpha[r] = __expf(m_r[r] - mn);
            l_r[r] = l_r[r] * alpha[r] + ts;
            m_r[r] = mn;
            Ps[w][(quad * 4 + r) * 40 + lr] = (_Float16)e0;
            Ps[w][(quad * 4 + r) * 40 + 16 + lr] = (_Float16)e1;
        }

        // ---- O = O*alpha + P V  (A-frag from per-wave Ps, B-frag from Vl) ----
#pragma unroll
        for (int n = 0; n < 8; ++n)
#pragma unroll
            for (int r = 0; r < 4; ++r) Oacc[n][r] *= alpha[r];

        const half8 af = *(const half8*)&Ps[w][lr * 40 + quad * 8];
#pragma unroll
        for (int n = 0; n < 8; ++n) {
            const half8 bv = *(const half8*)&Vl[(n * 16 + lr) * 32 + quad * 8];
            Oacc[n] = __builtin_amdgcn_mfma_f32_16x16x32_f16(af, bv, Oacc[n], 0, 0, 0);
        }
        __syncthreads();
    }

    // ---- normalize, LDS round-trip for coalesced f16 store ----
    float inv[4];
#pragma unroll
    for (int r = 0; r < 4; ++r) inv[r] = 1.f / l_r[r];
    _Float16* Ol = KV;  // reuse (all K/V reads fenced by loop-end barrier)
#pragma unroll
    for (int n = 0; n < 8; ++n)
#pragma unroll
        for (int r = 0; r < 4; ++r)
            Ol[(w * 16 + quad * 4 + r) * 128 + n * 16 + lr] = (_Float16)(Oacc[n][r] * inv[r]);
    __syncthreads();
#pragma unroll
    for (int it = 0; it < 4; ++it) {
        const int idx = tid + it * 256;
        const int row = idx >> 4, c8 = idx & 15;   // 64 rows x 16 half8 groups
        *(half8*)(Aout + (size_t)(q0 + row) * DD + h * HDIM + c8 * 8) =
            *(const half8*)&Ol[row * 128 + c8 * 8];
    }
}

// ---------------------------------------------------------------------------
// Launch: 4 kernels (was 6). ws (f16, 4M elems = 8MB each): xh, Wqt, Wkt,
// Wvt, Wot, Qh, Kh, Vt = 64 MB. Attn output reuses xh (dead after qkv_gemm).
// ---------------------------------------------------------------------------
extern "C" void kernel_launch(void* const* d_in, const int* in_sizes, int n_in,
                              void* d_out, int out_size, void* d_ws, size_t ws_size,
                              hipStream_t stream) {
    const float* x  = (const float*)d_in[0];
    const float* Wq = (const float*)d_in[1];
    const float* Wk = (const float*)d_in[2];
    const float* Wv = (const float*)d_in[3];
    const float* Wo = (const float*)d_in[4];
    const float* sn = (const float*)d_in[5];
    const float* cs = (const float*)d_in[6];
    const int* doc  = (const int*)d_in[7];
    float* out = (float*)d_out;

    const size_t NE = (size_t)TT * DD;
    _Float16* xh  = (_Float16*)d_ws;
    _Float16* Wqt = xh  + NE;
    _Float16* Wkt = Wqt + NE;
    _Float16* Wvt = Wkt + NE;
    _Float16* Wot = Wvt + NE;
    _Float16* Qh  = Wot + NE;
    _Float16* Kh  = Qh  + NE;
    _Float16* Vt  = Kh  + NE;
    _Float16* Abh = xh;  // reuse: xh consumed by qkv_gemm before attn writes

    const dim3 bb(256);

    prep_kernel<<<dim3(DD / 32, DD / 32, 5), bb, 0, stream>>>(x, Wq, Wk, Wv, Wo,
                                                              xh, Wqt, Wkt, Wvt, Wot);
    qkv_gemm_kernel<<<dim3(DD / 128, TT / 128, 3), bb, 0, stream>>>(xh, Wqt, Wkt, Wvt,
                                                                    sn, cs, Qh, Kh, Vt);
    attn_kernel<<<dim3(TT / 64, NH), bb, 0, stream>>>(Qh, Kh, Vt, doc, Abh);
    ogemm_kernel<<<dim3(DD / 128, TT / 128), bb, 0, stream>>>(Abh, Wot, out);
}

// Round 7
// 269.175 us; speedup vs baseline: 1.0706x; 1.0706x over previous
//
#include <hip/hip_runtime.h>

// Problem constants: B=1, T=2048, D=2048, H=16, HD=128
#define TT 2048
#define DD 2048
#define NH 16
#define HDIM 128

typedef _Float16 half8 __attribute__((ext_vector_type(8)));
typedef _Float16 half4 __attribute__((ext_vector_type(4)));
typedef float floatx4 __attribute__((ext_vector_type(4)));

// ---------------------------------------------------------------------------
// Fused prep: z=0 -> straight fp32->f16 convert of x tile;
// z=1..4 -> W[K][N] fp32 -> f16 Wt[N][K] transpose+convert (32x32 LDS tile).
// ---------------------------------------------------------------------------
__global__ __launch_bounds__(256) void prep_kernel(const float* __restrict__ x,
                                                   const float* __restrict__ W1,
                                                   const float* __restrict__ W2,
                                                   const float* __restrict__ W3,
                                                   const float* __restrict__ W4,
                                                   _Float16* __restrict__ xh,
                                                   _Float16* __restrict__ O1,
                                                   _Float16* __restrict__ O2,
                                                   _Float16* __restrict__ O3,
                                                   _Float16* __restrict__ O4) {
    const int tx = threadIdx.x & 7;    // *4 cols
    const int ty = threadIdx.x >> 3;   // 0..31
    const int k0 = blockIdx.y * 32;
    const int n0 = blockIdx.x * 32;
    const int z = blockIdx.z;

    if (z == 0) {  // straight convert
        const float4 v = *(const float4*)(x + (size_t)(k0 + ty) * DD + n0 + tx * 4);
        half4 o;
        o[0] = (_Float16)v.x; o[1] = (_Float16)v.y;
        o[2] = (_Float16)v.z; o[3] = (_Float16)v.w;
        *(half4*)(xh + (size_t)(k0 + ty) * DD + n0 + tx * 4) = o;
        return;
    }
    const float* W = z == 1 ? W1 : (z == 2 ? W2 : (z == 3 ? W3 : W4));
    _Float16* O = z == 1 ? O1 : (z == 2 ? O2 : (z == 3 ? O3 : O4));
    __shared__ float T[32][33];
    const float4 v = *(const float4*)(W + (size_t)(k0 + ty) * DD + n0 + tx * 4);
    T[ty][tx * 4 + 0] = v.x;
    T[ty][tx * 4 + 1] = v.y;
    T[ty][tx * 4 + 2] = v.z;
    T[ty][tx * 4 + 3] = v.w;
    __syncthreads();
    half4 o;
    o[0] = (_Float16)T[tx * 4 + 0][ty];
    o[1] = (_Float16)T[tx * 4 + 1][ty];
    o[2] = (_Float16)T[tx * 4 + 2][ty];
    o[3] = (_Float16)T[tx * 4 + 3][ty];
    *(half4*)(O + (size_t)(n0 + ty) * DD + k0 + tx * 4) = o;
}

// ---------------------------------------------------------------------------
// MFMA f16 GEMM body (R5-verified). MODE: 0 = fp32 C[row][col],
// 1 = f16 C[row][col], 2 = f16 transposed C[col][row].
// Register-lean epilogue (VGPR 80) — R6 showed +16 VGPR here costs 30 us.
// ---------------------------------------------------------------------------
template <int MODE>
__device__ __forceinline__ void hgemm_body(const _Float16* __restrict__ A,
                                           const _Float16* __restrict__ Bt,
                                           float* __restrict__ Cf,
                                           _Float16* __restrict__ Ch,
                                           const int row0, const int col0) {
    __shared__ __align__(16) _Float16 Al[128 * 32];
    __shared__ __align__(16) _Float16 Bl[128 * 32];

    const int tid = threadIdx.x;
    const int lane = tid & 63;
    const int w = tid >> 6;
    const int quad = lane >> 4;
    const int lr = lane & 15;
    const int wr = (w >> 1) * 64;
    const int wc = (w & 1) * 64;

    floatx4 acc[4][4];
#pragma unroll
    for (int i = 0; i < 4; ++i)
#pragma unroll
        for (int j = 0; j < 4; ++j)
            acc[i][j] = (floatx4){0.f, 0.f, 0.f, 0.f};

    const int subrow = lane >> 2;
    const int lblk = lane & 3;

    for (int k0 = 0; k0 < DD; k0 += 32) {
#pragma unroll
        for (int i = 0; i < 2; ++i) {
            const int ch = w * 2 + i;
            const int r = ch * 16 + subrow;
            const int gb = (lblk + (r >> 1)) & 3;
            const _Float16* ga = A + (size_t)(row0 + r) * DD + k0 + gb * 8;
            __builtin_amdgcn_global_load_lds(
                (const __attribute__((address_space(1))) void*)ga,
                (__attribute__((address_space(3))) void*)(Al + ch * 512), 16, 0, 0);
            const _Float16* gbp = Bt + (size_t)(col0 + r) * DD + k0 + gb * 8;
            __builtin_amdgcn_global_load_lds(
                (const __attribute__((address_space(1))) void*)gbp,
                (__attribute__((address_space(3))) void*)(Bl + ch * 512), 16, 0, 0);
        }
        __syncthreads();

        half8 af[4], bf[4];
#pragma unroll
        for (int i = 0; i < 4; ++i) {
            const int r = wr + i * 16 + lr;
            const int lb = (quad - (r >> 1)) & 3;
            af[i] = *(const half8*)&Al[r * 32 + lb * 8];
        }
#pragma unroll
        for (int j = 0; j < 4; ++j) {
            const int r = wc + j * 16 + lr;
            const int lb = (quad - (r >> 1)) & 3;
            bf[j] = *(const half8*)&Bl[r * 32 + lb * 8];
        }
#pragma unroll
        for (int i = 0; i < 4; ++i)
#pragma unroll
            for (int j = 0; j < 4; ++j)
                acc[i][j] = __builtin_amdgcn_mfma_f32_16x16x32_f16(af[i], bf[j], acc[i][j], 0, 0, 0);
        __syncthreads();
    }

    // epilogue: C/D layout col = lane&15, row = quad*4 + reg
#pragma unroll
    for (int i = 0; i < 4; ++i)
#pragma unroll
        for (int j = 0; j < 4; ++j) {
            const int col = col0 + wc + j * 16 + lr;
#pragma unroll
            for (int r = 0; r < 4; ++r) {
                const int row = row0 + wr + i * 16 + quad * 4 + r;
                if (MODE == 0) Cf[(size_t)row * DD + col] = acc[i][j][r];
                if (MODE == 1) Ch[(size_t)row * DD + col] = (_Float16)acc[i][j][r];
                if (MODE == 2) Ch[(size_t)col * DD + row] = (_Float16)acc[i][j][r];
            }
        }
}

// QKV fused: z=0 -> Qh (f16), z=1 -> Kh (f16), z=2 -> Vt (f16, transposed)
__global__ __launch_bounds__(256) void qkv_gemm_kernel(const _Float16* __restrict__ xh,
                                                       const _Float16* __restrict__ Wqt,
                                                       const _Float16* __restrict__ Wkt,
                                                       const _Float16* __restrict__ Wvt,
                                                       _Float16* __restrict__ Qh,
                                                       _Float16* __restrict__ Kh,
                                                       _Float16* __restrict__ Vt) {
    const int row0 = blockIdx.y * 128, col0 = blockIdx.x * 128;
    if (blockIdx.z == 0)      hgemm_body<1>(xh, Wqt, nullptr, Qh, row0, col0);
    else if (blockIdx.z == 1) hgemm_body<1>(xh, Wkt, nullptr, Kh, row0, col0);
    else                      hgemm_body<2>(xh, Wvt, nullptr, Vt, row0, col0);
}

__global__ __launch_bounds__(256) void ogemm_kernel(const _Float16* __restrict__ Ah,
                                                    const _Float16* __restrict__ Wot,
                                                    float* __restrict__ C) {
    hgemm_body<0>(Ah, Wot, C, nullptr, blockIdx.y * 128, blockIdx.x * 128);
}

// ---------------------------------------------------------------------------
// RoPE in-place on f16 Q and K (R5-verified; fp32 math, one f16 rounding).
// ---------------------------------------------------------------------------
__global__ __launch_bounds__(256) void rope_f16_kernel(_Float16* __restrict__ Qh,
                                                       _Float16* __restrict__ Kh,
                                                       const float* __restrict__ sn,
                                                       const float* __restrict__ cs) {
    const int idx = blockIdx.x * 256 + threadIdx.x;  // T*16*16 threads
    const int i = (idx & 15) * 4;
    const int h = (idx >> 4) & 15;
    const int t = idx >> 8;
    const size_t base = (size_t)t * DD + h * HDIM + i;
    half4 qa = *(half4*)(Qh + base), qb = *(half4*)(Qh + base + 64);
    half4 ka = *(half4*)(Kh + base), kb = *(half4*)(Kh + base + 64);
    half4 qa2, qb2, ka2, kb2;
#pragma unroll
    for (int j = 0; j < 4; ++j) {
        const float s1 = sn[t * HDIM + i + j];
        const float c1 = cs[t * HDIM + i + j];
        const float s2 = sn[t * HDIM + i + 64 + j];
        const float c2 = cs[t * HDIM + i + 64 + j];
        qa2[j] = (_Float16)((float)qa[j] * c1 - (float)qb[j] * s1);
        qb2[j] = (_Float16)((float)qb[j] * c2 + (float)qa[j] * s2);
        ka2[j] = (_Float16)((float)ka[j] * c1 - (float)kb[j] * s1);
        kb2[j] = (_Float16)((float)kb[j] * c2 + (float)ka[j] * s2);
    }
    *(half4*)(Qh + base) = qa2;
    *(half4*)(Qh + base + 64) = qb2;
    *(half4*)(Kh + base) = ka2;
    *(half4*)(Kh + base + 64) = kb2;
}

// ---------------------------------------------------------------------------
// MFMA flash attention (R5-verified, unchanged). Block = 4 waves, BQ=64,
// BS=32. Q frags in registers; K chunk-swizzled via global_load_lds; V from
// pre-transposed Vt[d][t]. P round-trips per-wave LDS. Doc mask via -1e30
// annihilation.
// ---------------------------------------------------------------------------
__global__ __launch_bounds__(256) void attn_kernel(const _Float16* __restrict__ Qh,
                                                   const _Float16* __restrict__ Kh,
                                                   const _Float16* __restrict__ Vt,
                                                   const int* __restrict__ doc_ids,
                                                   _Float16* __restrict__ Aout) {
    __shared__ __align__(16) _Float16 KV[32 * 128 + 128 * 32];  // Kl | Vl (16KB)
    __shared__ __align__(16) _Float16 Ps[4][16 * 40];           // per-wave P
    __shared__ int sdoc[32];
    _Float16* Kl = KV;
    _Float16* Vl = KV + 32 * 128;

    const int tid = threadIdx.x;
    const int lane = tid & 63;
    const int w = tid >> 6;
    const int quad = lane >> 4;
    const int lr = lane & 15;
    const int h = blockIdx.y;
    const int q0 = blockIdx.x * 64;

    // Q fragments (A-layout): row = q0 + w*16 + lr, k = c*32 + quad*8 + j
    const int qrow = q0 + w * 16 + lr;
    half8 qf[4];
#pragma unroll
    for (int c = 0; c < 4; ++c)
        qf[c] = *(const half8*)(Qh + (size_t)qrow * DD + h * HDIM + c * 32 + quad * 8);

    // docs of this lane's C-layout rows (quad*4 + r)
    int qd[4];
#pragma unroll
    for (int r = 0; r < 4; ++r)
        qd[r] = doc_ids[q0 + w * 16 + quad * 4 + r];

    float m_r[4], l_r[4];
    floatx4 Oacc[8];
#pragma unroll
    for (int r = 0; r < 4; ++r) { m_r[r] = -1e30f; l_r[r] = 0.f; }
#pragma unroll
    for (int n = 0; n < 8; ++n) Oacc[n] = (floatx4){0.f, 0.f, 0.f, 0.f};

    // binary search: first index with doc == doc_ids[q0]
    const int d0 = doc_ids[q0];
    int lo = 0, hi = q0;
    while (lo < hi) {
        const int mid = (lo + hi) >> 1;
        if (doc_ids[mid] < d0) lo = mid + 1; else hi = mid;
    }
    const int s_begin = lo & ~31;

    for (int s0 = s_begin; s0 < q0 + 64; s0 += 32) {
        // ---- stage K (chunk-swizzled) + Vt ----
#pragma unroll
        for (int i = 0; i < 2; ++i) {
            const int ch = w * 2 + i;
            {   // K: 4 rows x 256B per instr; LDS[r][p] holds global chunk (p - r)&15
                const int r = ch * 4 + (lane >> 4);
                const int g = ((lane & 15) - r) & 15;
                const _Float16* src = Kh + (size_t)(s0 + r) * DD + h * HDIM + g * 8;
                __builtin_amdgcn_global_load_lds(
                    (const __attribute__((address_space(1))) void*)src,
                    (__attribute__((address_space(3))) void*)(Kl + ch * 512), 16, 0, 0);
            }
            {   // Vt: 16 rows x 64B per instr, natural [d][s] layout
                const int dl = ch * 16 + (lane >> 2);
                const _Float16* src = Vt + (size_t)(h * HDIM + dl) * TT + s0 + (lane & 3) * 8;
                __builtin_amdgcn_global_load_lds(
                    (const __attribute__((address_space(1))) void*)src,
                    (__attribute__((address_space(3))) void*)(Vl + ch * 512), 16, 0, 0);
            }
        }
        if (tid < 32) sdoc[tid] = doc_ids[s0 + tid];
        __syncthreads();

        // ---- S = Q K^T : two 16x16 col-blocks ----
        floatx4 S0 = (floatx4){0.f, 0.f, 0.f, 0.f};
        floatx4 S1 = (floatx4){0.f, 0.f, 0.f, 0.f};
#pragma unroll
        for (int c = 0; c < 4; ++c) {
            const int p = (c * 4 + quad + lr) & 15;
            half8 b0 = *(const half8*)&Kl[(lr) * 128 + p * 8];
            half8 b1 = *(const half8*)&Kl[(16 + lr) * 128 + p * 8];
            S0 = __builtin_amdgcn_mfma_f32_16x16x32_f16(qf[c], b0, S0, 0, 0, 0);
            S1 = __builtin_amdgcn_mfma_f32_16x16x32_f16(qf[c], b1, S1, 0, 0, 0);
        }

        // ---- mask + online softmax (C layout: col=lr, row=quad*4+r) ----
        const float scale = 0.08838834764831845f;
        float alpha[4];
#pragma unroll
        for (int r = 0; r < 4; ++r) {
            const int qg = q0 + w * 16 + quad * 4 + r;
            const bool v0 = (s0 + lr <= qg) && (sdoc[lr] == qd[r]);
            const bool v1 = (s0 + 16 + lr <= qg) && (sdoc[16 + lr] == qd[r]);
            const float x0 = v0 ? S0[r] * scale : -1e30f;
            const float x1 = v1 ? S1[r] * scale : -1e30f;
            float m = fmaxf(x0, x1);
            m = fmaxf(m, __shfl_xor(m, 1));
            m = fmaxf(m, __shfl_xor(m, 2));
            m = fmaxf(m, __shfl_xor(m, 4));
            m = fmaxf(m, __shfl_xor(m, 8));
            const float mn = fmaxf(m_r[r], m);
            const float e0 = __expf(x0 - mn);
            const float e1 = __expf(x1 - mn);
            float ts = e0 + e1;
            ts += __shfl_xor(ts, 1);
            ts += __shfl_xor(ts, 2);
            ts += __shfl_xor(ts, 4);
            ts += __shfl_xor(ts, 8);
            alpha[r] = __expf(m_r[r] - mn);
            l_r[r] = l_r[r] * alpha[r] + ts;
            m_r[r] = mn;
            Ps[w][(quad * 4 + r) * 40 + lr] = (_Float16)e0;
            Ps[w][(quad * 4 + r) * 40 + 16 + lr] = (_Float16)e1;
        }

        // ---- O = O*alpha + P V  (A-frag from per-wave Ps, B-frag from Vl) ----
#pragma unroll
        for (int n = 0; n < 8; ++n)
#pragma unroll
            for (int r = 0; r < 4; ++r) Oacc[n][r] *= alpha[r];

        const half8 af = *(const half8*)&Ps[w][lr * 40 + quad * 8];
#pragma unroll
        for (int n = 0; n < 8; ++n) {
            const half8 bv = *(const half8*)&Vl[(n * 16 + lr) * 32 + quad * 8];
            Oacc[n] = __builtin_amdgcn_mfma_f32_16x16x32_f16(af, bv, Oacc[n], 0, 0, 0);
        }
        __syncthreads();
    }

    // ---- normalize, LDS round-trip for coalesced f16 store ----
    float inv[4];
#pragma unroll
    for (int r = 0; r < 4; ++r) inv[r] = 1.f / l_r[r];
    _Float16* Ol = KV;  // reuse (all K/V reads fenced by loop-end barrier)
#pragma unroll
    for (int n = 0; n < 8; ++n)
#pragma unroll
        for (int r = 0; r < 4; ++r)
            Ol[(w * 16 + quad * 4 + r) * 128 + n * 16 + lr] = (_Float16)(Oacc[n][r] * inv[r]);
    __syncthreads();
#pragma unroll
    for (int it = 0; it < 4; ++it) {
        const int idx = tid + it * 256;
        const int row = idx >> 4, c8 = idx & 15;   // 64 rows x 16 half8 groups
        *(half8*)(Aout + (size_t)(q0 + row) * DD + h * HDIM + c8 * 8) =
            *(const half8*)&Ol[row * 128 + c8 * 8];
    }
}

// ---------------------------------------------------------------------------
// Launch: 5 kernels. ws (f16, 4M elems = 8MB each): xh, Wqt, Wkt, Wvt, Wot,
// Qh, Kh, Vt = 64 MB. Attn output reuses xh (dead after qkv_gemm).
// ---------------------------------------------------------------------------
extern "C" void kernel_launch(void* const* d_in, const int* in_sizes, int n_in,
                              void* d_out, int out_size, void* d_ws, size_t ws_size,
                              hipStream_t stream) {
    const float* x  = (const float*)d_in[0];
    const float* Wq = (const float*)d_in[1];
    const float* Wk = (const float*)d_in[2];
    const float* Wv = (const float*)d_in[3];
    const float* Wo = (const float*)d_in[4];
    const float* sn = (const float*)d_in[5];
    const float* cs = (const float*)d_in[6];
    const int* doc  = (const int*)d_in[7];
    float* out = (float*)d_out;

    const size_t NE = (size_t)TT * DD;
    _Float16* xh  = (_Float16*)d_ws;
    _Float16* Wqt = xh  + NE;
    _Float16* Wkt = Wqt + NE;
    _Float16* Wvt = Wkt + NE;
    _Float16* Wot = Wvt + NE;
    _Float16* Qh  = Wot + NE;
    _Float16* Kh  = Qh  + NE;
    _Float16* Vt  = Kh  + NE;
    _Float16* Abh = xh;  // reuse: xh consumed by qkv_gemm before attn writes

    const dim3 bb(256);

    prep_kernel<<<dim3(DD / 32, DD / 32, 5), bb, 0, stream>>>(x, Wq, Wk, Wv, Wo,
                                                              xh, Wqt, Wkt, Wvt, Wot);
    qkv_gemm_kernel<<<dim3(DD / 128, TT / 128, 3), bb, 0, stream>>>(xh, Wqt, Wkt, Wvt,
                                                                    Qh, Kh, Vt);
    rope_f16_kernel<<<dim3((TT * NH * 16) / 256), bb, 0, stream>>>(Qh, Kh, sn, cs);
    attn_kernel<<<dim3(TT / 64, NH), bb, 0, stream>>>(Qh, Kh, Vt, doc, Abh);
    ogemm_kernel<<<dim3(DD / 128, TT / 128), bb, 0, stream>>>(Abh, Wot, out);
}